// Round 3
// baseline (763.393 us; speedup 1.0000x reference)
//
#include <hip/hip_runtime.h>
#include <math.h>

#define NS 65536   // total samples = 2048 rays * 32
#define NRAYS 2048

// ---- workspace layout (float offsets) ----
#define WS_H     2621440u                   // hT     [64][65536]
#define WS_X     6815744u                   // xT     [256][65536] (bottleneck)
#define WS_Y     23592960u                  // yT     [256][65536]
#define WS_DW0   40370176u                  // dirW0  [2048][256]
#define WS_DW1   40894464u                  // dirW1  [2048][256]
// total 41418752 floats = 165.7 MB

// ---- output layout (float offsets in d_out) ----
#define OUT_DENS 196608
#define OUT_RGB  262144

// =====================================================================
// Kernel 1: contract + hash-grid encode + d1 GEMV (fused).
// One thread per sample; feats[40] stay in registers; d1 weights in
// LDS, read wave-uniform (broadcast, conflict-free).
// =====================================================================
__global__ __launch_bounds__(256) void encode_d1_kernel(
    const float* __restrict__ coords, const float* __restrict__ emb,
    const float* __restrict__ w_d1, const float* __restrict__ b_d1,
    float* __restrict__ cw_out, float* __restrict__ hT)
{
    const int offs[10] = {0, 4920, 40864, 315496, 2412648, 4509800,
                          6606952, 8704104, 10801256, 12898408};
    __shared__ float Ws[40*64];   // w_d1 [40][64]
    __shared__ float Bs[64];
    int t = threadIdx.x;
#pragma unroll
    for (int i = 0; i < 10; ++i) Ws[i*256 + t] = w_d1[i*256 + t];
    if (t < 64) Bs[t] = b_d1[t];

    int i = blockIdx.x * 256 + t;
    float x = coords[3*i+0], y = coords[3*i+1], z = coords[3*i+2];
    float m2 = x*x + y*y + z*z;
    m2 = fmaxf(m2, 1.1920928955078125e-07f);
    float cx = x, cy = y, cz = z;
    if (m2 > 1.0f) {
        float s = (2.0f*sqrtf(m2) - 1.0f) / m2;
        cx *= s; cy *= s; cz *= s;
    }
    cx *= 0.5f; cy *= 0.5f; cz *= 0.5f;   // /BOUND
    cw_out[3*i+0] = cx; cw_out[3*i+1] = cy; cw_out[3*i+2] = cz;
    float u0 = (cx + 2.0f) * 0.25f;
    float u1 = (cy + 2.0f) * 0.25f;
    float u2 = (cz + 2.0f) * 0.25f;

    float feats[40];
#pragma unroll
    for (int l = 0; l < 10; ++l) {
        int res = 16 << l;
        int res1 = res + 1;
        float scale = (float)(res - 1);
        float p0 = u0*scale + 0.5f, p1 = u1*scale + 0.5f, p2 = u2*scale + 0.5f;
        float f0 = floorf(p0), f1 = floorf(p1), f2 = floorf(p2);
        float fr0 = p0 - f0, fr1 = p1 - f1, fr2 = p2 - f2;
        unsigned g0 = (unsigned)(int)f0, g1 = (unsigned)(int)f1, g2 = (unsigned)(int)f2;
        float a0 = 0.f, a1 = 0.f, a2 = 0.f, a3 = 0.f;
#pragma unroll
        for (int c = 0; c < 8; ++c) {
            unsigned ox = c & 1u, oy = (c >> 1) & 1u, oz = (c >> 2) & 1u;
            unsigned qx = g0 + ox, qy = g1 + oy, qz = g2 + oz;
            unsigned idx;
            if (l >= 3) idx = (qx ^ (qy*2654435761u) ^ (qz*805459861u)) & 2097151u;
            else        idx = qx + qy*(unsigned)res1 + qz*(unsigned)(res1*res1);
            const float4 e = *(const float4*)(emb + 4u*((unsigned)offs[l] + idx));
            float w = (ox ? fr0 : 1.0f-fr0) * (oy ? fr1 : 1.0f-fr1) * (oz ? fr2 : 1.0f-fr2);
            a0 = fmaf(w, e.x, a0); a1 = fmaf(w, e.y, a1);
            a2 = fmaf(w, e.z, a2); a3 = fmaf(w, e.w, a3);
        }
        feats[l*4+0] = a0; feats[l*4+1] = a1;
        feats[l*4+2] = a2; feats[l*4+3] = a3;
    }
    __syncthreads();
    // d1 GEMV: h[j] = relu(b[j] + sum_k feats[k]*W[k][j]), 4 chunks of 16
#pragma unroll
    for (int j0 = 0; j0 < 64; j0 += 16) {
        float acc[16];
#pragma unroll
        for (int jj = 0; jj < 16; ++jj) acc[jj] = Bs[j0+jj];
#pragma unroll
        for (int k = 0; k < 40; ++k) {
            float fv = feats[k];
            const float4* wp = (const float4*)&Ws[k*64 + j0];
#pragma unroll
            for (int q = 0; q < 4; ++q) {
                float4 w = wp[q];
                acc[q*4+0] = fmaf(fv, w.x, acc[q*4+0]);
                acc[q*4+1] = fmaf(fv, w.y, acc[q*4+1]);
                acc[q*4+2] = fmaf(fv, w.z, acc[q*4+2]);
                acc[q*4+3] = fmaf(fv, w.w, acc[q*4+3]);
            }
        }
#pragma unroll
        for (int jj = 0; jj < 16; ++jj)
            hT[(j0+jj)*NS + i] = fmaxf(acc[jj], 0.f);
    }
}

// =====================================================================
// Kernel 2: per-ray dir encoding folded into per-ray bias tables.
// dirW0[ray][j] = b_r0[j] + sum_d de[d] * w_r0[256+d][j]
// dirW1[ray][j] = b_r1[j] + sum_d de[d] * w_r1[512+d][j]
// =====================================================================
__global__ __launch_bounds__(256) void dir_kernel(
    const float* __restrict__ viewdirs,
    const float* __restrict__ w_r0, const float* __restrict__ b_r0,
    const float* __restrict__ w_r1, const float* __restrict__ b_r1,
    float* __restrict__ dirW0, float* __restrict__ dirW1)
{
    __shared__ float de[27];
    int ray = blockIdx.x, t = threadIdx.x;
    if (t < 27) {
        float v;
        if (t < 3) v = viewdirs[3*ray + t];
        else {
            int k = (t - 3) % 12;                       // k = s*3 + d
            float b = viewdirs[3*ray + (k % 3)] * (float)(1 << (k / 3));
            v = (t < 15) ? sinf(b) : sinf(b + 1.5707964f);
        }
        de[t] = v;
    }
    __syncthreads();
    float a0 = b_r0[t], a1 = b_r1[t];
#pragma unroll
    for (int d = 0; d < 27; ++d) {
        a0 = fmaf(de[d], w_r0[(256+d)*256 + t], a0);
        a1 = fmaf(de[d], w_r1[(512+d)*256 + t], a1);
    }
    dirW0[ray*256 + t] = a0;
    dirW1[ray*256 + t] = a1;
}

// =====================================================================
// Shared chunk routine for BN=256 GEMMs: one BK=32 K-chunk.
// A tile: flat [512] float4 = [32 k-rows][16 m-quads]; thread t writes
// slots t and 256+t -> each 16-lane quarter writes 256B contiguous
// (conflict-free). W tile [32][256] stored block-permuted with r-stride
// padded to 514 float4s: compute read (16 lanes x 16B contiguous) is
// conflict-free and the scatter store lands 2-way (free).
//   slot(r,k,tn) = r*514 + k*16 + tn  holds  W[k][tn*16 + r*4 .. +3]
// =====================================================================
__device__ __forceinline__ void gemm_chunk256(
    const float* __restrict__ aSrc,   // srcT + k0*NS + m0
    const float* __restrict__ wSrc,   // W + k0*256
    int t, float4* As4, float4* Ws4, float (&acc)[4][16])
{
    int ar = t >> 4, am = (t & 15) << 2;
    float4 a0 = *(const float4*)(aSrc + ar*NS + am);
    float4 a1 = *(const float4*)(aSrc + (ar+16)*NS + am);
    const float4* wsrc4 = (const float4*)wSrc;
    float4 wtmp[8];
#pragma unroll
    for (int i = 0; i < 8; ++i) wtmp[i] = wsrc4[i*256 + t];
    __syncthreads();                    // WAR: previous chunk's reads done
    As4[t]       = a0;
    As4[256 + t] = a1;
#pragma unroll
    for (int i = 0; i < 8; ++i) {
        int q = i*256 + t;              // chunk float4 id, row-major [32][64]
        int kq = q >> 6;
        int tnq = (q >> 2) & 15;
        int rq = q & 3;
        Ws4[rq*514 + kq*16 + tnq] = wtmp[i];
    }
    __syncthreads();                    // RAW: tiles visible
    int tn = t & 15, tm = t >> 4;
#pragma unroll
    for (int k = 0; k < 32; ++k) {
        float4 a = As4[k*16 + tm];
        float av[4] = {a.x, a.y, a.z, a.w};
#pragma unroll
        for (int r = 0; r < 4; ++r) {
            float4 w = Ws4[r*514 + k*16 + tn];   // = W[k][tn*16+r*4 .. +3]
            float wv[4] = {w.x, w.y, w.z, w.w};
#pragma unroll
            for (int ii = 0; ii < 4; ++ii)
#pragma unroll
                for (int cc = 0; cc < 4; ++cc)
                    acc[ii][r*4+cc] = fmaf(av[ii], wv[cc], acc[ii][r*4+cc]);
        }
    }
}

// =====================================================================
// Kernel 3: d2 — x[256] = h[64] @ w_d2 + b_d2 ; density = softplus(x0-1)
// =====================================================================
__global__ __launch_bounds__(256) void gemm_d2_kernel(
    const float* __restrict__ hT, const float* __restrict__ w_d2,
    const float* __restrict__ b_d2, float* __restrict__ xT,
    float* __restrict__ dens)
{
    __shared__ float4 As4[512];
    __shared__ float4 Ws4[2056];
    int t = threadIdx.x;
    int m0 = blockIdx.x * 64;
    float acc[4][16] = {};
    for (int c = 0; c < 2; ++c)
        gemm_chunk256(hT + c*32*NS + m0, w_d2 + c*32*256, t, As4, Ws4, acc);
    int tn = t & 15, tm = t >> 4;
#pragma unroll
    for (int jj = 0; jj < 16; ++jj) {
        int j = tn*16 + jj;
        float bj = b_d2[j];
        float4 v;
        v.x = acc[0][jj] + bj; v.y = acc[1][jj] + bj;
        v.z = acc[2][jj] + bj; v.w = acc[3][jj] + bj;
        *(float4*)(xT + j*NS + m0 + tm*4) = v;
        if (tn == 0 && jj == 0) {
            float vv[4] = {v.x, v.y, v.z, v.w};
#pragma unroll
            for (int ii = 0; ii < 4; ++ii) {
                float zz = vv[ii] - 1.0f;   // DENSITY_BIAS
                dens[m0 + tm*4 + ii] = fmaxf(zz, 0.f) + log1pf(expf(-fabsf(zz)));
            }
        }
    }
}

// =====================================================================
// Kernel 4: r0 — y = relu(bottleneck @ w_r0[0:256] + dirW0[ray])
// =====================================================================
__global__ __launch_bounds__(256) void gemm_r0_kernel(
    const float* __restrict__ xT, const float* __restrict__ w_r0,
    const float* __restrict__ dirW0, float* __restrict__ yT)
{
    __shared__ float4 As4[512];
    __shared__ float4 Ws4[2056];
    int t = threadIdx.x;
    int m0 = blockIdx.x * 64;
    float acc[4][16] = {};
    for (int c = 0; c < 8; ++c)
        gemm_chunk256(xT + c*32*NS + m0, w_r0 + c*32*256, t, As4, Ws4, acc);
    int tn = t & 15, tm = t >> 4;
    const float* dw = dirW0 + ((m0 + tm*4) >> 5) * 256;
#pragma unroll
    for (int jj = 0; jj < 16; ++jj) {
        int j = tn*16 + jj;
        float bj = dw[j];
        float4 v;
        v.x = fmaxf(acc[0][jj] + bj, 0.f);
        v.y = fmaxf(acc[1][jj] + bj, 0.f);
        v.z = fmaxf(acc[2][jj] + bj, 0.f);
        v.w = fmaxf(acc[3][jj] + bj, 0.f);
        *(float4*)(yT + j*NS + m0 + tm*4) = v;
    }
}

// =====================================================================
// Kernel 5: r1 + rgb — y1 = relu(y@w_r1[0:256] + x@w_r1[256:512] + dirW1)
//           rgb = sigmoid(y1 @ w_rgb + b_rgb)*1.002 - 0.001  (fused via
//           16-lane shfl_xor reduction; y1 never hits memory)
// =====================================================================
__global__ __launch_bounds__(256) void gemm_r1_kernel(
    const float* __restrict__ yT, const float* __restrict__ xT,
    const float* __restrict__ w_r1, const float* __restrict__ dirW1,
    const float* __restrict__ w_rgb, const float* __restrict__ b_rgb,
    float* __restrict__ rgb)
{
    __shared__ float4 As4[512];
    __shared__ float4 Ws4[2056];
    int t = threadIdx.x;
    int m0 = blockIdx.x * 64;
    float acc[4][16] = {};
    for (int c = 0; c < 8; ++c)
        gemm_chunk256(yT + c*32*NS + m0, w_r1 + c*32*256, t, As4, Ws4, acc);
    for (int c = 0; c < 8; ++c)
        gemm_chunk256(xT + c*32*NS + m0, w_r1 + (256 + c*32)*256, t, As4, Ws4, acc);
    int tn = t & 15, tm = t >> 4;
    const float* dw = dirW1 + ((m0 + tm*4) >> 5) * 256;
    float p[4][3] = {};
#pragma unroll
    for (int jj = 0; jj < 16; ++jj) {
        int j = tn*16 + jj;
        float bj = dw[j];
        float w0 = w_rgb[j*3+0], w1 = w_rgb[j*3+1], w2 = w_rgb[j*3+2];
#pragma unroll
        for (int ii = 0; ii < 4; ++ii) {
            float yv = fmaxf(acc[ii][jj] + bj, 0.f);
            p[ii][0] = fmaf(yv, w0, p[ii][0]);
            p[ii][1] = fmaf(yv, w1, p[ii][1]);
            p[ii][2] = fmaf(yv, w2, p[ii][2]);
        }
    }
    // reduce partial rgb across the 16 tn-lanes (consecutive lanes, same wave)
#pragma unroll
    for (int mask = 1; mask < 16; mask <<= 1)
#pragma unroll
        for (int ii = 0; ii < 4; ++ii)
#pragma unroll
            for (int cc = 0; cc < 3; ++cc)
                p[ii][cc] += __shfl_xor(p[ii][cc], mask, 64);
    if (tn == 0) {
#pragma unroll
        for (int ii = 0; ii < 4; ++ii) {
            int s = m0 + tm*4 + ii;
#pragma unroll
            for (int cc = 0; cc < 3; ++cc) {
                float v = p[ii][cc] + b_rgb[cc];
                float sg = 1.0f / (1.0f + expf(-v));
                rgb[s*3 + cc] = sg * 1.002f - 0.001f;
            }
        }
    }
}

// =====================================================================
extern "C" void kernel_launch(void* const* d_in, const int* in_sizes, int n_in,
                              void* d_out, int out_size, void* d_ws, size_t ws_size,
                              hipStream_t stream)
{
    const float* coords   = (const float*)d_in[0];
    const float* viewdirs = (const float*)d_in[1];
    const float* emb      = (const float*)d_in[2];
    const float* w_d1     = (const float*)d_in[3];
    const float* b_d1     = (const float*)d_in[4];
    const float* w_d2     = (const float*)d_in[5];
    const float* b_d2     = (const float*)d_in[6];
    const float* w_r0     = (const float*)d_in[7];
    const float* b_r0     = (const float*)d_in[8];
    const float* w_r1     = (const float*)d_in[9];
    const float* b_r1     = (const float*)d_in[10];
    const float* w_rgb    = (const float*)d_in[11];
    const float* b_rgb    = (const float*)d_in[12];

    float* out  = (float*)d_out;
    float* ws   = (float*)d_ws;
    float* cw   = out;
    float* dens = out + OUT_DENS;
    float* rgb  = out + OUT_RGB;

    float* hT     = ws + WS_H;
    float* xT     = ws + WS_X;
    float* yT     = ws + WS_Y;
    float* dirW0  = ws + WS_DW0;
    float* dirW1  = ws + WS_DW1;

    encode_d1_kernel<<<NS/256, 256, 0, stream>>>(coords, emb, w_d1, b_d1, cw, hT);
    dir_kernel<<<NRAYS, 256, 0, stream>>>(viewdirs, w_r0, b_r0, w_r1, b_r1, dirW0, dirW1);
    gemm_d2_kernel<<<NS/64, 256, 0, stream>>>(hT, w_d2, b_d2, xT, dens);
    gemm_r0_kernel<<<NS/64, 256, 0, stream>>>(xT, w_r0, dirW0, yT);
    gemm_r1_kernel<<<NS/64, 256, 0, stream>>>(yT, xT, w_r1, dirW1, w_rgb, b_rgb, rgb);
}

// Round 5
// 508.860 us; speedup vs baseline: 1.5002x; 1.5002x over previous
//
#include <hip/hip_runtime.h>
#include <math.h>

#define NS 65536   // total samples = 2048 rays * 32
#define NRAYS 2048

typedef __attribute__((ext_vector_type(8))) short short8;
typedef __attribute__((ext_vector_type(4))) float f32x4;
typedef unsigned short u16;

// ---- workspace layout (BYTE offsets) ----
#define OFF_FEATS 0ull          // f32 featsT [40][65536]          10.5 MB
#define OFF_HBF   10485760ull   // bf16 h  [65536][64]              8.4 MB
#define OFF_XBF   18874368ull   // bf16 x  [65536][256]            33.5 MB
#define OFF_YBF   52428800ull   // bf16 y  [65536][256]            33.5 MB
#define OFF_DW0   85983232ull   // f32 dirW0 [2048][256]            2.1 MB
#define OFF_DW1   88080384ull   // f32 dirW1 [2048][256]            2.1 MB
#define OFF_WD2T  90177536ull   // bf16 w_d2t [256][64]
#define OFF_WR0T  90210304ull   // bf16 w_r0t [256][256]
#define OFF_WR1T  90341376ull   // bf16 w_r1t [256][512]  (end ~90.6MB)

// ---- output layout (float offsets in d_out) ----
#define OUT_DENS 196608
#define OUT_RGB  262144

__device__ __forceinline__ u16 f2b(float f) {   // f32 -> bf16 RNE
    unsigned u = __builtin_bit_cast(unsigned, f);
    return (u16)((u + 0x7FFFu + ((u >> 16) & 1u)) >> 16);
}

// =====================================================================
// Kernel A: weight convert/transpose to bf16 n-major.
//   w_d2t[n][k]=w_d2[k][n] (64K), w_r0t[n][k]=w_r0[k][n] (k<256),
//   w_r1t[n][k]=w_r1[k][n] (k<512)
// =====================================================================
__global__ __launch_bounds__(256) void cvt_weights(
    const float* __restrict__ w_d2, const float* __restrict__ w_r0,
    const float* __restrict__ w_r1, u16* __restrict__ wd2t,
    u16* __restrict__ wr0t, u16* __restrict__ wr1t)
{
    int idx = blockIdx.x * 256 + threadIdx.x;
    if (idx < 16384)  wd2t[idx] = f2b(w_d2[(idx & 63)  * 256 + (idx >> 6)]);
    if (idx < 65536)  wr0t[idx] = f2b(w_r0[(idx & 255) * 256 + (idx >> 8)]);
    if (idx < 131072) wr1t[idx] = f2b(w_r1[(idx & 511) * 256 + (idx >> 9)]);
}

// =====================================================================
// Kernel B: per-ray dir encoding folded into per-ray bias tables (f32).
// =====================================================================
__global__ __launch_bounds__(256) void dir_kernel(
    const float* __restrict__ viewdirs,
    const float* __restrict__ w_r0, const float* __restrict__ b_r0,
    const float* __restrict__ w_r1, const float* __restrict__ b_r1,
    float* __restrict__ dirW0, float* __restrict__ dirW1)
{
    __shared__ float de[27];
    int ray = blockIdx.x, t = threadIdx.x;
    if (t < 27) {
        float v;
        if (t < 3) v = viewdirs[3*ray + t];
        else {
            int k = (t - 3) % 12;                       // k = s*3 + d
            float b = viewdirs[3*ray + (k % 3)] * (float)(1 << (k / 3));
            v = (t < 15) ? sinf(b) : sinf(b + 1.5707964f);
        }
        de[t] = v;
    }
    __syncthreads();
    float a0 = b_r0[t], a1 = b_r1[t];
#pragma unroll
    for (int d = 0; d < 27; ++d) {
        a0 = fmaf(de[d], w_r0[(256+d)*256 + t], a0);
        a1 = fmaf(de[d], w_r1[(512+d)*256 + t], a1);
    }
    dirW0[ray*256 + t] = a0;
    dirW1[ray*256 + t] = a1;
}

// =====================================================================
// Kernel C: contract + hash-grid encode, one thread per (sample, level).
// Grid = 10 levels * 256 sample-blocks; block-uniform level.
// =====================================================================
__global__ __launch_bounds__(256) void encode_kernel(
    const float* __restrict__ coords, const float* __restrict__ emb,
    float* __restrict__ cw_out, float* __restrict__ featsT)
{
    int t = threadIdx.x;
    int l = blockIdx.x >> 8;
    int i = ((blockIdx.x & 255) << 8) + t;
    float x = coords[3*i], y = coords[3*i+1], z = coords[3*i+2];
    float m2 = fmaxf(x*x + y*y + z*z, 1.1920928955078125e-07f);
    float cx = x, cy = y, cz = z;
    if (m2 > 1.0f) { float s = (2.0f*sqrtf(m2) - 1.0f)/m2; cx*=s; cy*=s; cz*=s; }
    cx *= 0.5f; cy *= 0.5f; cz *= 0.5f;   // /BOUND
    if (l == 0) { cw_out[3*i]=cx; cw_out[3*i+1]=cy; cw_out[3*i+2]=cz; }
    float u0 = (cx + 2.0f)*0.25f, u1 = (cy + 2.0f)*0.25f, u2 = (cz + 2.0f)*0.25f;

    int res = 16 << l;
    int res1 = res + 1;
    float scale = (float)(res - 1);
    unsigned off = (l >= 3) ? 315496u + (unsigned)(l-3)*2097152u
                            : (l == 0 ? 0u : (l == 1 ? 4920u : 40864u));
    float p0 = u0*scale + 0.5f, p1 = u1*scale + 0.5f, p2 = u2*scale + 0.5f;
    float f0 = floorf(p0), f1 = floorf(p1), f2 = floorf(p2);
    float fr0 = p0-f0, fr1 = p1-f1, fr2 = p2-f2;
    unsigned g0 = (unsigned)(int)f0, g1 = (unsigned)(int)f1, g2 = (unsigned)(int)f2;
    float a0=0.f, a1=0.f, a2=0.f, a3=0.f;
    bool use_hash = (l >= 3);
#pragma unroll
    for (int c = 0; c < 8; ++c) {
        unsigned ox = c & 1u, oy = (c >> 1) & 1u, oz = (c >> 2) & 1u;
        unsigned qx = g0 + ox, qy = g1 + oy, qz = g2 + oz;
        unsigned idx;
        if (use_hash) idx = (qx ^ (qy*2654435761u) ^ (qz*805459861u)) & 2097151u;
        else          idx = qx + qy*(unsigned)res1 + qz*(unsigned)(res1*res1);
        const float4 e = *(const float4*)(emb + 4u*(off + idx));
        float w = (ox ? fr0 : 1.0f-fr0) * (oy ? fr1 : 1.0f-fr1) * (oz ? fr2 : 1.0f-fr2);
        a0 = fmaf(w, e.x, a0); a1 = fmaf(w, e.y, a1);
        a2 = fmaf(w, e.z, a2); a3 = fmaf(w, e.w, a3);
    }
    featsT[(4*l+0)*NS + i] = a0;
    featsT[(4*l+1)*NS + i] = a1;
    featsT[(4*l+2)*NS + i] = a2;
    featsT[(4*l+3)*NS + i] = a3;
}

// =====================================================================
// Kernel D: d1 (f32 VALU) + fused f32 density head.
//   h = relu(feats[40] @ w_d1 + b_d1)  -> h_bf row-major bf16 [NS][64]
//   dens = softplus(h . w_d2[:,0] + b_d2[0] - 1)   (f32 path, exact-ish)
// =====================================================================
__global__ __launch_bounds__(256) void gemm_d1_kernel(
    const float* __restrict__ featsT, const float* __restrict__ w_d1,
    const float* __restrict__ b_d1, const float* __restrict__ w_d2,
    const float* __restrict__ b_d2, u16* __restrict__ h_bf,
    float* __restrict__ dens)
{
    __shared__ float As[40][256];
    __shared__ float Ws[40*64];
    __shared__ float wc0[64];
    int t = threadIdx.x;
    int m0 = blockIdx.x * 256;
#pragma unroll
    for (int k = 0; k < 40; ++k) As[k][t] = featsT[k*NS + m0 + t];
#pragma unroll
    for (int i = 0; i < 10; ++i) Ws[i*256 + t] = w_d1[i*256 + t];
    if (t < 64) wc0[t] = w_d2[t*256];
    __syncthreads();
    int tn = t & 3, tm = t >> 2;       // tn: col group (16), tm: sample quad
    float acc[4][16] = {};
#pragma unroll
    for (int k = 0; k < 40; ++k) {
        float4 a = *(const float4*)&As[k][tm*4];
        float av[4] = {a.x, a.y, a.z, a.w};
        const float4* wp = (const float4*)&Ws[k*64 + tn*16];
#pragma unroll
        for (int r = 0; r < 4; ++r) {
            float4 w = wp[r];
            float wv[4] = {w.x, w.y, w.z, w.w};
#pragma unroll
            for (int ii = 0; ii < 4; ++ii)
#pragma unroll
                for (int cc = 0; cc < 4; ++cc)
                    acc[ii][r*4+cc] = fmaf(av[ii], wv[cc], acc[ii][r*4+cc]);
        }
    }
    float p[4] = {0.f, 0.f, 0.f, 0.f};
#pragma unroll
    for (int jj = 0; jj < 16; ++jj) {
        int j = tn*16 + jj;
        float bj = b_d1[j], w0 = wc0[j];
#pragma unroll
        for (int ii = 0; ii < 4; ++ii) {
            float h = fmaxf(acc[ii][jj] + bj, 0.f);
            acc[ii][jj] = h;
            p[ii] = fmaf(h, w0, p[ii]);
        }
    }
#pragma unroll
    for (int ii = 0; ii < 4; ++ii) {
        int s = m0 + tm*4 + ii;
        unsigned u[8];
#pragma unroll
        for (int q = 0; q < 8; ++q)
            u[q] = (unsigned)f2b(acc[ii][2*q]) | ((unsigned)f2b(acc[ii][2*q+1]) << 16);
        uint4 v0 = {u[0], u[1], u[2], u[3]};
        uint4 v1 = {u[4], u[5], u[6], u[7]};
        *(uint4*)(h_bf + (size_t)s*64 + tn*16)     = v0;
        *(uint4*)(h_bf + (size_t)s*64 + tn*16 + 8) = v1;
    }
    // density: reduce partials over the 4 tn lanes (lane bits 0..1)
#pragma unroll
    for (int ii = 0; ii < 4; ++ii) {
        p[ii] += __shfl_xor(p[ii], 1, 64);
        p[ii] += __shfl_xor(p[ii], 2, 64);
    }
    if (tn == 0) {
        float b0 = b_d2[0];
#pragma unroll
        for (int ii = 0; ii < 4; ++ii) {
            float z = p[ii] + b0 - 1.0f;   // DENSITY_BIAS
            dens[m0 + tm*4 + ii] = fmaxf(z, 0.f) + log1pf(expf(-fabsf(z)));
        }
    }
}

// =====================================================================
// MFMA kernels. Block=256thr=4 waves, wave owns 32 rows (one ray), N=256.
// A frag: lane l holds A[m0+(l&15)][kb+(l>>4)*8 .. +7] (16B load)
// B frag: lane l holds W[kb+(l>>4)*8 .. +7][nt*16+(l&15)] via n-major Wt
// C frag: row = (l>>4)*4+r, col = l&15   (m89-verified)
// =====================================================================
#define MFMA __builtin_amdgcn_mfma_f32_16x16x32_bf16

// Kernel E: d2 — x = h @ w_d2 + b_d2 (no relu), bf16 out row-major
__global__ __launch_bounds__(256) void mfma_d2(
    const u16* __restrict__ h_bf, const u16* __restrict__ wt,
    const float* __restrict__ b_d2, u16* __restrict__ xbf)
{
    int t = threadIdx.x, lane = t & 63, w = t >> 6;
    int m0 = blockIdx.x*128 + w*32;
    int rl = lane & 15, kg = (lane >> 4) * 8;
    f32x4 zero = {0.f,0.f,0.f,0.f};
    f32x4 acc[2][16];
#pragma unroll
    for (int a = 0; a < 2; ++a)
#pragma unroll
        for (int b = 0; b < 16; ++b) acc[a][b] = zero;
    const u16* pA0 = h_bf + (size_t)(m0 + rl)*64 + kg;
    const u16* pA1 = h_bf + (size_t)(m0 + 16 + rl)*64 + kg;
    const u16* pB  = wt + rl*64 + kg;
#pragma unroll
    for (int ks = 0; ks < 2; ++ks) {
        int kb = ks*32;
        short8 a0 = *(const short8*)(pA0 + kb);
        short8 a1 = *(const short8*)(pA1 + kb);
#pragma unroll
        for (int nt = 0; nt < 16; ++nt) {
            short8 b = *(const short8*)(pB + nt*1024 + kb);
            acc[0][nt] = MFMA(a0, b, acc[0][nt], 0, 0, 0);
            acc[1][nt] = MFMA(a1, b, acc[1][nt], 0, 0, 0);
        }
    }
    int ro = (lane >> 4) * 4;
#pragma unroll
    for (int nt = 0; nt < 16; ++nt) {
        int col = nt*16 + rl;
        float bias = b_d2[col];
#pragma unroll
        for (int mt = 0; mt < 2; ++mt)
#pragma unroll
            for (int r = 0; r < 4; ++r)
                xbf[(size_t)(m0 + mt*16 + ro + r)*256 + col] = f2b(acc[mt][nt][r] + bias);
    }
}

// Kernel F: r0 — y = relu(x @ w_r0 + dirW0[ray]), bf16 out row-major
__global__ __launch_bounds__(256) void mfma_r0(
    const u16* __restrict__ xbf, const u16* __restrict__ wt,
    const float* __restrict__ dirW0, u16* __restrict__ ybf)
{
    int t = threadIdx.x, lane = t & 63, w = t >> 6;
    int m0 = blockIdx.x*128 + w*32;
    int rl = lane & 15, kg = (lane >> 4) * 8;
    f32x4 zero = {0.f,0.f,0.f,0.f};
    f32x4 acc[2][16];
#pragma unroll
    for (int a = 0; a < 2; ++a)
#pragma unroll
        for (int b = 0; b < 16; ++b) acc[a][b] = zero;
    const u16* pA0 = xbf + (size_t)(m0 + rl)*256 + kg;
    const u16* pA1 = xbf + (size_t)(m0 + 16 + rl)*256 + kg;
    const u16* pB  = wt + rl*256 + kg;
#pragma unroll
    for (int ks = 0; ks < 8; ++ks) {
        int kb = ks*32;
        short8 a0 = *(const short8*)(pA0 + kb);
        short8 a1 = *(const short8*)(pA1 + kb);
#pragma unroll
        for (int nt = 0; nt < 16; ++nt) {
            short8 b = *(const short8*)(pB + nt*4096 + kb);
            acc[0][nt] = MFMA(a0, b, acc[0][nt], 0, 0, 0);
            acc[1][nt] = MFMA(a1, b, acc[1][nt], 0, 0, 0);
        }
    }
    const float* dir = dirW0 + (m0 >> 5)*256;   // wave == one ray
    int ro = (lane >> 4) * 4;
#pragma unroll
    for (int nt = 0; nt < 16; ++nt) {
        int col = nt*16 + rl;
        float bias = dir[col];
#pragma unroll
        for (int mt = 0; mt < 2; ++mt)
#pragma unroll
            for (int r = 0; r < 4; ++r)
                ybf[(size_t)(m0 + mt*16 + ro + r)*256 + col] =
                    f2b(fmaxf(acc[mt][nt][r] + bias, 0.f));
    }
}

// Kernel G: r1 + rgb — y1 = relu(y@W1a + x@W1b + dirW1[ray]) in regs,
//           rgb = sigmoid(y1 @ w_rgb + b_rgb)*1.002 - 0.001
__global__ __launch_bounds__(256) void mfma_r1(
    const u16* __restrict__ ybf, const u16* __restrict__ xbf,
    const u16* __restrict__ wt, const float* __restrict__ dirW1,
    const float* __restrict__ w_rgb, const float* __restrict__ b_rgb,
    float* __restrict__ rgb)
{
    int t = threadIdx.x, lane = t & 63, w = t >> 6;
    int m0 = blockIdx.x*128 + w*32;
    int rl = lane & 15, kg = (lane >> 4) * 8;
    f32x4 zero = {0.f,0.f,0.f,0.f};
    f32x4 acc[2][16];
#pragma unroll
    for (int a = 0; a < 2; ++a)
#pragma unroll
        for (int b = 0; b < 16; ++b) acc[a][b] = zero;
    const u16* pAy0 = ybf + (size_t)(m0 + rl)*256 + kg;
    const u16* pAy1 = ybf + (size_t)(m0 + 16 + rl)*256 + kg;
    const u16* pAx0 = xbf + (size_t)(m0 + rl)*256 + kg;
    const u16* pAx1 = xbf + (size_t)(m0 + 16 + rl)*256 + kg;
    const u16* pB   = wt + rl*512 + kg;
#pragma unroll
    for (int ks = 0; ks < 16; ++ks) {
        int kb = ks*32;
        int kl = (ks & 7)*32;
        short8 a0 = (ks < 8) ? *(const short8*)(pAy0 + kl) : *(const short8*)(pAx0 + kl);
        short8 a1 = (ks < 8) ? *(const short8*)(pAy1 + kl) : *(const short8*)(pAx1 + kl);
#pragma unroll
        for (int nt = 0; nt < 16; ++nt) {
            short8 b = *(const short8*)(pB + nt*8192 + kb);
            acc[0][nt] = MFMA(a0, b, acc[0][nt], 0, 0, 0);
            acc[1][nt] = MFMA(a1, b, acc[1][nt], 0, 0, 0);
        }
    }
    const float* dir = dirW1 + (m0 >> 5)*256;
    float p[2][4][3];
#pragma unroll
    for (int mt = 0; mt < 2; ++mt)
#pragma unroll
        for (int r = 0; r < 4; ++r)
            p[mt][r][0] = p[mt][r][1] = p[mt][r][2] = 0.f;
#pragma unroll
    for (int nt = 0; nt < 16; ++nt) {
        int col = nt*16 + rl;
        float dv = dir[col];
        float w0 = w_rgb[col*3], w1 = w_rgb[col*3+1], w2 = w_rgb[col*3+2];
#pragma unroll
        for (int mt = 0; mt < 2; ++mt)
#pragma unroll
            for (int r = 0; r < 4; ++r) {
                float y1 = fmaxf(acc[mt][nt][r] + dv, 0.f);
                p[mt][r][0] = fmaf(y1, w0, p[mt][r][0]);
                p[mt][r][1] = fmaf(y1, w1, p[mt][r][1]);
                p[mt][r][2] = fmaf(y1, w2, p[mt][r][2]);
            }
    }
    // reduce over the 16 col-lanes (lane bits 0..3)
#pragma unroll
    for (int mask = 1; mask < 16; mask <<= 1)
#pragma unroll
        for (int mt = 0; mt < 2; ++mt)
#pragma unroll
            for (int r = 0; r < 4; ++r)
#pragma unroll
                for (int c = 0; c < 3; ++c)
                    p[mt][r][c] += __shfl_xor(p[mt][r][c], mask, 64);
    if (rl == 0) {
        int ro = (lane >> 4) * 4;
#pragma unroll
        for (int mt = 0; mt < 2; ++mt)
#pragma unroll
            for (int r = 0; r < 4; ++r) {
                int row = m0 + mt*16 + ro + r;
#pragma unroll
                for (int c = 0; c < 3; ++c) {
                    float v = p[mt][r][c] + b_rgb[c];
                    float sg = 1.0f / (1.0f + expf(-v));
                    rgb[row*3 + c] = sg * 1.002f - 0.001f;
                }
            }
    }
}

// =====================================================================
extern "C" void kernel_launch(void* const* d_in, const int* in_sizes, int n_in,
                              void* d_out, int out_size, void* d_ws, size_t ws_size,
                              hipStream_t stream)
{
    const float* coords   = (const float*)d_in[0];
    const float* viewdirs = (const float*)d_in[1];
    const float* emb      = (const float*)d_in[2];
    const float* w_d1     = (const float*)d_in[3];
    const float* b_d1     = (const float*)d_in[4];
    const float* w_d2     = (const float*)d_in[5];
    const float* b_d2     = (const float*)d_in[6];
    const float* w_r0     = (const float*)d_in[7];
    const float* b_r0     = (const float*)d_in[8];
    const float* w_r1     = (const float*)d_in[9];
    const float* b_r1     = (const float*)d_in[10];
    const float* w_rgb    = (const float*)d_in[11];
    const float* b_rgb    = (const float*)d_in[12];

    float* out  = (float*)d_out;
    float* cw   = out;
    float* dens = out + OUT_DENS;
    float* rgb  = out + OUT_RGB;

    char* wsB = (char*)d_ws;
    float* featsT = (float*)(wsB + OFF_FEATS);
    u16*   h_bf   = (u16*)(wsB + OFF_HBF);
    u16*   xbf    = (u16*)(wsB + OFF_XBF);
    u16*   ybf    = (u16*)(wsB + OFF_YBF);
    float* dirW0  = (float*)(wsB + OFF_DW0);
    float* dirW1  = (float*)(wsB + OFF_DW1);
    u16*   wd2t   = (u16*)(wsB + OFF_WD2T);
    u16*   wr0t   = (u16*)(wsB + OFF_WR0T);
    u16*   wr1t   = (u16*)(wsB + OFF_WR1T);

    cvt_weights<<<512, 256, 0, stream>>>(w_d2, w_r0, w_r1, wd2t, wr0t, wr1t);
    dir_kernel<<<NRAYS, 256, 0, stream>>>(viewdirs, w_r0, b_r0, w_r1, b_r1, dirW0, dirW1);
    encode_kernel<<<2560, 256, 0, stream>>>(coords, emb, cw, featsT);
    gemm_d1_kernel<<<NS/256, 256, 0, stream>>>(featsT, w_d1, b_d1, w_d2, b_d2, h_bf, dens);
    mfma_d2<<<NS/128, 256, 0, stream>>>(h_bf, wd2t, b_d2, xbf);
    mfma_r0<<<NS/128, 256, 0, stream>>>(xbf, wr0t, dirW0, ybf);
    mfma_r1<<<NS/128, 256, 0, stream>>>(ybf, xbf, wr1t, dirW1, w_rgb, b_rgb, rgb);
}

// Round 6
// 495.517 us; speedup vs baseline: 1.5406x; 1.0269x over previous
//
#include <hip/hip_runtime.h>
#include <math.h>

#define NS 65536   // total samples = 2048 rays * 32
#define NRAYS 2048

typedef __attribute__((ext_vector_type(8))) short short8;
typedef __attribute__((ext_vector_type(4))) float f32x4;
typedef unsigned short u16;

// ---- workspace layout (BYTE offsets) ----
#define OFF_FEATS 0ull          // f32 featsT [40][65536]          10.5 MB
#define OFF_HBF   10485760ull   // bf16 h  [65536][64]              8.4 MB
#define OFF_XBF   18874368ull   // bf16 x  [65536][256]            33.5 MB
#define OFF_DW0   85983232ull   // f32 dirW0 [2048][256]            2.1 MB
#define OFF_DW1   88080384ull   // f32 dirW1 [2048][256]            2.1 MB
#define OFF_WD2T  90177536ull   // bf16 w_d2t [256][64]
#define OFF_WR0T  90210304ull   // bf16 w_r0t [256][256]
#define OFF_WR1T  90341376ull   // bf16 w_r1t [256][512]  (end ~90.6MB)

// ---- output layout (float offsets in d_out) ----
#define OUT_DENS 196608
#define OUT_RGB  262144

__device__ __forceinline__ u16 f2b(float f) {   // f32 -> bf16 RNE
    unsigned u = __builtin_bit_cast(unsigned, f);
    return (u16)((u + 0x7FFFu + ((u >> 16) & 1u)) >> 16);
}

// =====================================================================
// Kernel A: weight convert/transpose to bf16 n-major.
// =====================================================================
__global__ __launch_bounds__(256) void cvt_weights(
    const float* __restrict__ w_d2, const float* __restrict__ w_r0,
    const float* __restrict__ w_r1, u16* __restrict__ wd2t,
    u16* __restrict__ wr0t, u16* __restrict__ wr1t)
{
    int idx = blockIdx.x * 256 + threadIdx.x;
    if (idx < 16384)  wd2t[idx] = f2b(w_d2[(idx & 63)  * 256 + (idx >> 6)]);
    if (idx < 65536)  wr0t[idx] = f2b(w_r0[(idx & 255) * 256 + (idx >> 8)]);
    if (idx < 131072) wr1t[idx] = f2b(w_r1[(idx & 511) * 256 + (idx >> 9)]);
}

// =====================================================================
// Kernel B: per-ray dir encoding folded into per-ray bias tables (f32).
// =====================================================================
__global__ __launch_bounds__(256) void dir_kernel(
    const float* __restrict__ viewdirs,
    const float* __restrict__ w_r0, const float* __restrict__ b_r0,
    const float* __restrict__ w_r1, const float* __restrict__ b_r1,
    float* __restrict__ dirW0, float* __restrict__ dirW1)
{
    __shared__ float de[27];
    int ray = blockIdx.x, t = threadIdx.x;
    if (t < 27) {
        float v;
        if (t < 3) v = viewdirs[3*ray + t];
        else {
            int k = (t - 3) % 12;                       // k = s*3 + d
            float b = viewdirs[3*ray + (k % 3)] * (float)(1 << (k / 3));
            v = (t < 15) ? sinf(b) : sinf(b + 1.5707964f);
        }
        de[t] = v;
    }
    __syncthreads();
    float a0 = b_r0[t], a1 = b_r1[t];
#pragma unroll
    for (int d = 0; d < 27; ++d) {
        a0 = fmaf(de[d], w_r0[(256+d)*256 + t], a0);
        a1 = fmaf(de[d], w_r1[(512+d)*256 + t], a1);
    }
    dirW0[ray*256 + t] = a0;
    dirW1[ray*256 + t] = a1;
}

// =====================================================================
// Kernel C: contract + hash-grid encode, one thread per (sample, level).
// =====================================================================
__global__ __launch_bounds__(256) void encode_kernel(
    const float* __restrict__ coords, const float* __restrict__ emb,
    float* __restrict__ cw_out, float* __restrict__ featsT)
{
    int t = threadIdx.x;
    int l = blockIdx.x >> 8;
    int i = ((blockIdx.x & 255) << 8) + t;
    float x = coords[3*i], y = coords[3*i+1], z = coords[3*i+2];
    float m2 = fmaxf(x*x + y*y + z*z, 1.1920928955078125e-07f);
    float cx = x, cy = y, cz = z;
    if (m2 > 1.0f) { float s = (2.0f*sqrtf(m2) - 1.0f)/m2; cx*=s; cy*=s; cz*=s; }
    cx *= 0.5f; cy *= 0.5f; cz *= 0.5f;   // /BOUND
    if (l == 0) { cw_out[3*i]=cx; cw_out[3*i+1]=cy; cw_out[3*i+2]=cz; }
    float u0 = (cx + 2.0f)*0.25f, u1 = (cy + 2.0f)*0.25f, u2 = (cz + 2.0f)*0.25f;

    int res = 16 << l;
    int res1 = res + 1;
    float scale = (float)(res - 1);
    unsigned off = (l >= 3) ? 315496u + (unsigned)(l-3)*2097152u
                            : (l == 0 ? 0u : (l == 1 ? 4920u : 40864u));
    float p0 = u0*scale + 0.5f, p1 = u1*scale + 0.5f, p2 = u2*scale + 0.5f;
    float f0 = floorf(p0), f1 = floorf(p1), f2 = floorf(p2);
    float fr0 = p0-f0, fr1 = p1-f1, fr2 = p2-f2;
    unsigned g0 = (unsigned)(int)f0, g1 = (unsigned)(int)f1, g2 = (unsigned)(int)f2;
    float a0=0.f, a1=0.f, a2=0.f, a3=0.f;
    bool use_hash = (l >= 3);
#pragma unroll
    for (int c = 0; c < 8; ++c) {
        unsigned ox = c & 1u, oy = (c >> 1) & 1u, oz = (c >> 2) & 1u;
        unsigned qx = g0 + ox, qy = g1 + oy, qz = g2 + oz;
        unsigned idx;
        if (use_hash) idx = (qx ^ (qy*2654435761u) ^ (qz*805459861u)) & 2097151u;
        else          idx = qx + qy*(unsigned)res1 + qz*(unsigned)(res1*res1);
        const float4 e = *(const float4*)(emb + 4u*(off + idx));
        float w = (ox ? fr0 : 1.0f-fr0) * (oy ? fr1 : 1.0f-fr1) * (oz ? fr2 : 1.0f-fr2);
        a0 = fmaf(w, e.x, a0); a1 = fmaf(w, e.y, a1);
        a2 = fmaf(w, e.z, a2); a3 = fmaf(w, e.w, a3);
    }
    featsT[(4*l+0)*NS + i] = a0;
    featsT[(4*l+1)*NS + i] = a1;
    featsT[(4*l+2)*NS + i] = a2;
    featsT[(4*l+3)*NS + i] = a3;
}

// =====================================================================
// Kernel D: d1 (f32 VALU) + fused f32 density head.
// =====================================================================
__global__ __launch_bounds__(256) void gemm_d1_kernel(
    const float* __restrict__ featsT, const float* __restrict__ w_d1,
    const float* __restrict__ b_d1, const float* __restrict__ w_d2,
    const float* __restrict__ b_d2, u16* __restrict__ h_bf,
    float* __restrict__ dens)
{
    __shared__ float As[40][256];
    __shared__ float Ws[40*64];
    __shared__ float wc0[64];
    int t = threadIdx.x;
    int m0 = blockIdx.x * 256;
#pragma unroll
    for (int k = 0; k < 40; ++k) As[k][t] = featsT[k*NS + m0 + t];
#pragma unroll
    for (int i = 0; i < 10; ++i) Ws[i*256 + t] = w_d1[i*256 + t];
    if (t < 64) wc0[t] = w_d2[t*256];
    __syncthreads();
    int tn = t & 3, tm = t >> 2;       // tn: col group (16), tm: sample quad
    float acc[4][16] = {};
#pragma unroll
    for (int k = 0; k < 40; ++k) {
        float4 a = *(const float4*)&As[k][tm*4];
        float av[4] = {a.x, a.y, a.z, a.w};
        const float4* wp = (const float4*)&Ws[k*64 + tn*16];
#pragma unroll
        for (int r = 0; r < 4; ++r) {
            float4 w = wp[r];
            float wv[4] = {w.x, w.y, w.z, w.w};
#pragma unroll
            for (int ii = 0; ii < 4; ++ii)
#pragma unroll
                for (int cc = 0; cc < 4; ++cc)
                    acc[ii][r*4+cc] = fmaf(av[ii], wv[cc], acc[ii][r*4+cc]);
        }
    }
    float p[4] = {0.f, 0.f, 0.f, 0.f};
#pragma unroll
    for (int jj = 0; jj < 16; ++jj) {
        int j = tn*16 + jj;
        float bj = b_d1[j], w0 = wc0[j];
#pragma unroll
        for (int ii = 0; ii < 4; ++ii) {
            float h = fmaxf(acc[ii][jj] + bj, 0.f);
            acc[ii][jj] = h;
            p[ii] = fmaf(h, w0, p[ii]);
        }
    }
#pragma unroll
    for (int ii = 0; ii < 4; ++ii) {
        int s = m0 + tm*4 + ii;
        unsigned u[8];
#pragma unroll
        for (int q = 0; q < 8; ++q)
            u[q] = (unsigned)f2b(acc[ii][2*q]) | ((unsigned)f2b(acc[ii][2*q+1]) << 16);
        uint4 v0 = {u[0], u[1], u[2], u[3]};
        uint4 v1 = {u[4], u[5], u[6], u[7]};
        *(uint4*)(h_bf + (size_t)s*64 + tn*16)     = v0;
        *(uint4*)(h_bf + (size_t)s*64 + tn*16 + 8) = v1;
    }
    // density: reduce partials over the 4 tn lanes (lane bits 0..1)
#pragma unroll
    for (int ii = 0; ii < 4; ++ii) {
        p[ii] += __shfl_xor(p[ii], 1, 64);
        p[ii] += __shfl_xor(p[ii], 2, 64);
    }
    if (tn == 0) {
        float b0 = b_d2[0];
#pragma unroll
        for (int ii = 0; ii < 4; ++ii) {
            float z = p[ii] + b0 - 1.0f;   // DENSITY_BIAS
            dens[m0 + tm*4 + ii] = fmaxf(z, 0.f) + log1pf(expf(-fabsf(z)));
        }
    }
}

// =====================================================================
// MFMA kernels. Block=256thr=4 waves, wave owns 32 rows (one ray), N=256.
// A frag: lane l holds A[m0+(l&15)][kb+(l>>4)*8 .. +7] (16B load)
// B frag: lane l holds W[kb+(l>>4)*8 .. +7][nt*16+(l&15)] via n-major Wt
// C frag: row = (l>>4)*4+r, col = l&15   (m89-verified)
// LDS tiles [32 rows][256 cols] bf16, XOR-swizzled byte ^= (row&7)<<4.
// =====================================================================
#define MFMA __builtin_amdgcn_mfma_f32_16x16x32_bf16

// Kernel E: d2 — x = h @ w_d2 + b_d2 (no relu), bf16 out row-major.
// Epilogue staged through swizzled LDS tile for coalesced 16B stores.
__global__ __launch_bounds__(256) void mfma_d2(
    const u16* __restrict__ h_bf, const u16* __restrict__ wt,
    const float* __restrict__ b_d2, u16* __restrict__ xbf)
{
    __shared__ u16 xt[4][8192];   // 16 KB per wave
    int t = threadIdx.x, lane = t & 63, w = t >> 6;
    int m0 = blockIdx.x*128 + w*32;
    int rl = lane & 15, kg = (lane >> 4) * 8;
    f32x4 zero = {0.f,0.f,0.f,0.f};
    f32x4 acc[2][16];
#pragma unroll
    for (int a = 0; a < 2; ++a)
#pragma unroll
        for (int b = 0; b < 16; ++b) acc[a][b] = zero;
    const u16* pA0 = h_bf + (size_t)(m0 + rl)*64 + kg;
    const u16* pA1 = h_bf + (size_t)(m0 + 16 + rl)*64 + kg;
    const u16* pB  = wt + rl*64 + kg;
#pragma unroll
    for (int ks = 0; ks < 2; ++ks) {
        int kb = ks*32;
        short8 a0 = *(const short8*)(pA0 + kb);
        short8 a1 = *(const short8*)(pA1 + kb);
#pragma unroll
        for (int nt = 0; nt < 16; ++nt) {
            short8 b = *(const short8*)(pB + nt*1024 + kb);
            acc[0][nt] = MFMA(a0, b, acc[0][nt], 0, 0, 0);
            acc[1][nt] = MFMA(a1, b, acc[1][nt], 0, 0, 0);
        }
    }
    int ro = (lane >> 4) * 4;
    u16* xw = xt[w];
#pragma unroll
    for (int nt = 0; nt < 16; ++nt) {
        int col = nt*16 + rl;
        float bias = b_d2[col];
#pragma unroll
        for (int mt = 0; mt < 2; ++mt)
#pragma unroll
            for (int r = 0; r < 4; ++r) {
                int row = mt*16 + ro + r;
                unsigned byte = (unsigned)(row*512 + col*2) ^ ((unsigned)(row & 7) << 4);
                xw[byte >> 1] = f2b(acc[mt][nt][r] + bias);
            }
    }
    // coalesced write-out: 16 iters x (b128 LDS read + 16B global store)
#pragma unroll
    for (int it = 0; it < 16; ++it) {
        unsigned flat = it*1024u + (unsigned)lane*16u;     // byte offset in tile
        unsigned row = flat >> 9, off = flat & 511u;
        unsigned lb = flat ^ ((row & 7u) << 4);
        short8 v = *(const short8*)((const char*)xw + lb);
        *(short8*)(xbf + (size_t)(m0 + row)*256 + (off >> 1)) = v;
    }
}

// Kernel F: fused r0 + r1 + rgb.
//   acc0 = x @ W0 ; y = relu(acc0 + dirW0) -> wave-private swizzled LDS
//   acc1 = y @ W1[0:256] + x @ W1[256:512]
//   y1 = relu(acc1 + dirW1) ; rgb = sigmoid(y1 @ w_rgb + b_rgb)*1.002-0.001
__global__ __launch_bounds__(256) void mfma_tail(
    const u16* __restrict__ xbf, const u16* __restrict__ w0t,
    const u16* __restrict__ w1t, const float* __restrict__ dirW0,
    const float* __restrict__ dirW1, const float* __restrict__ w_rgb,
    const float* __restrict__ b_rgb, float* __restrict__ rgb)
{
    __shared__ u16 yt[4][8192];   // 16 KB per wave, wave-private
    int t = threadIdx.x, lane = t & 63, w = t >> 6;
    int m0 = blockIdx.x*128 + w*32;
    int rl = lane & 15, kg = (lane >> 4) * 8;
    int ro = (lane >> 4) * 4;
    f32x4 zero = {0.f,0.f,0.f,0.f};
    const u16* pA0 = xbf + (size_t)(m0 + rl)*256 + kg;
    const u16* pA1 = xbf + (size_t)(m0 + 16 + rl)*256 + kg;

    // ---- r0 ----
    f32x4 acc0[2][16];
#pragma unroll
    for (int a = 0; a < 2; ++a)
#pragma unroll
        for (int b = 0; b < 16; ++b) acc0[a][b] = zero;
    {
        const u16* pB = w0t + rl*256 + kg;
#pragma unroll
        for (int ks = 0; ks < 8; ++ks) {
            int kb = ks*32;
            short8 a0 = *(const short8*)(pA0 + kb);
            short8 a1 = *(const short8*)(pA1 + kb);
#pragma unroll
            for (int nt = 0; nt < 16; ++nt) {
                short8 b = *(const short8*)(pB + nt*4096 + kb);
                acc0[0][nt] = MFMA(a0, b, acc0[0][nt], 0, 0, 0);
                acc0[1][nt] = MFMA(a1, b, acc0[1][nt], 0, 0, 0);
            }
        }
    }
    // y = relu(acc0 + dir0) -> swizzled LDS tile
    {
        const float* dir0 = dirW0 + (m0 >> 5)*256;
        u16* yw = yt[w];
#pragma unroll
        for (int nt = 0; nt < 16; ++nt) {
            int col = nt*16 + rl;
            float bias = dir0[col];
#pragma unroll
            for (int mt = 0; mt < 2; ++mt)
#pragma unroll
                for (int r = 0; r < 4; ++r) {
                    int row = mt*16 + ro + r;
                    unsigned byte = (unsigned)(row*512 + col*2) ^ ((unsigned)(row & 7) << 4);
                    yw[byte >> 1] = f2b(fmaxf(acc0[mt][nt][r] + bias, 0.f));
                }
        }
    }
    // ---- r1 ----
    f32x4 acc1[2][16];
#pragma unroll
    for (int a = 0; a < 2; ++a)
#pragma unroll
        for (int b = 0; b < 16; ++b) acc1[a][b] = zero;
    {
        const u16* pB = w1t + rl*512;
        const char* ywc = (const char*)yt[w];
        unsigned sw = ((unsigned)(rl & 7)) << 4;
#pragma unroll
        for (int ks = 0; ks < 8; ++ks) {          // y-part, k in [0,256)
            int kb = ks*32;
            unsigned base = (unsigned)((kb + kg)*2);
            short8 a0 = *(const short8*)(ywc + (((unsigned)(rl*512)       + base) ^ sw));
            short8 a1 = *(const short8*)(ywc + (((unsigned)((16+rl)*512)  + base) ^ sw));
#pragma unroll
            for (int nt = 0; nt < 16; ++nt) {
                short8 b = *(const short8*)(pB + nt*8192 + kg + kb);
                acc1[0][nt] = MFMA(a0, b, acc1[0][nt], 0, 0, 0);
                acc1[1][nt] = MFMA(a1, b, acc1[1][nt], 0, 0, 0);
            }
        }
#pragma unroll
        for (int ks = 8; ks < 16; ++ks) {         // x-part, k in [256,512)
            int kb = ks*32;
            int kl = kb - 256;
            short8 a0 = *(const short8*)(pA0 + kl);
            short8 a1 = *(const short8*)(pA1 + kl);
#pragma unroll
            for (int nt = 0; nt < 16; ++nt) {
                short8 b = *(const short8*)(pB + nt*8192 + kg + kb);
                acc1[0][nt] = MFMA(a0, b, acc1[0][nt], 0, 0, 0);
                acc1[1][nt] = MFMA(a1, b, acc1[1][nt], 0, 0, 0);
            }
        }
    }
    // ---- rgb epilogue ----
    const float* dir1 = dirW1 + (m0 >> 5)*256;
    float p[2][4][3];
#pragma unroll
    for (int mt = 0; mt < 2; ++mt)
#pragma unroll
        for (int r = 0; r < 4; ++r)
            p[mt][r][0] = p[mt][r][1] = p[mt][r][2] = 0.f;
#pragma unroll
    for (int nt = 0; nt < 16; ++nt) {
        int col = nt*16 + rl;
        float dv = dir1[col];
        float w0 = w_rgb[col*3], w1 = w_rgb[col*3+1], w2 = w_rgb[col*3+2];
#pragma unroll
        for (int mt = 0; mt < 2; ++mt)
#pragma unroll
            for (int r = 0; r < 4; ++r) {
                float y1 = fmaxf(acc1[mt][nt][r] + dv, 0.f);
                p[mt][r][0] = fmaf(y1, w0, p[mt][r][0]);
                p[mt][r][1] = fmaf(y1, w1, p[mt][r][1]);
                p[mt][r][2] = fmaf(y1, w2, p[mt][r][2]);
            }
    }
#pragma unroll
    for (int mask = 1; mask < 16; mask <<= 1)
#pragma unroll
        for (int mt = 0; mt < 2; ++mt)
#pragma unroll
            for (int r = 0; r < 4; ++r)
#pragma unroll
                for (int c = 0; c < 3; ++c)
                    p[mt][r][c] += __shfl_xor(p[mt][r][c], mask, 64);
    if (rl == 0) {
#pragma unroll
        for (int mt = 0; mt < 2; ++mt)
#pragma unroll
            for (int r = 0; r < 4; ++r) {
                int row = m0 + mt*16 + ro + r;
#pragma unroll
                for (int c = 0; c < 3; ++c) {
                    float v = p[mt][r][c] + b_rgb[c];
                    float sg = 1.0f / (1.0f + expf(-v));
                    rgb[row*3 + c] = sg * 1.002f - 0.001f;
                }
            }
    }
}

// =====================================================================
extern "C" void kernel_launch(void* const* d_in, const int* in_sizes, int n_in,
                              void* d_out, int out_size, void* d_ws, size_t ws_size,
                              hipStream_t stream)
{
    const float* coords   = (const float*)d_in[0];
    const float* viewdirs = (const float*)d_in[1];
    const float* emb      = (const float*)d_in[2];
    const float* w_d1     = (const float*)d_in[3];
    const float* b_d1     = (const float*)d_in[4];
    const float* w_d2     = (const float*)d_in[5];
    const float* b_d2     = (const float*)d_in[6];
    const float* w_r0     = (const float*)d_in[7];
    const float* b_r0     = (const float*)d_in[8];
    const float* w_r1     = (const float*)d_in[9];
    const float* b_r1     = (const float*)d_in[10];
    const float* w_rgb    = (const float*)d_in[11];
    const float* b_rgb    = (const float*)d_in[12];

    float* out  = (float*)d_out;
    float* cw   = out;
    float* dens = out + OUT_DENS;
    float* rgb  = out + OUT_RGB;

    char* wsB = (char*)d_ws;
    float* featsT = (float*)(wsB + OFF_FEATS);
    u16*   h_bf   = (u16*)(wsB + OFF_HBF);
    u16*   xbf    = (u16*)(wsB + OFF_XBF);
    float* dirW0  = (float*)(wsB + OFF_DW0);
    float* dirW1  = (float*)(wsB + OFF_DW1);
    u16*   wd2t   = (u16*)(wsB + OFF_WD2T);
    u16*   wr0t   = (u16*)(wsB + OFF_WR0T);
    u16*   wr1t   = (u16*)(wsB + OFF_WR1T);

    cvt_weights<<<512, 256, 0, stream>>>(w_d2, w_r0, w_r1, wd2t, wr0t, wr1t);
    dir_kernel<<<NRAYS, 256, 0, stream>>>(viewdirs, w_r0, b_r0, w_r1, b_r1, dirW0, dirW1);
    encode_kernel<<<2560, 256, 0, stream>>>(coords, emb, cw, featsT);
    gemm_d1_kernel<<<NS/256, 256, 0, stream>>>(featsT, w_d1, b_d1, w_d2, b_d2, h_bf, dens);
    mfma_d2<<<NS/128, 256, 0, stream>>>(h_bf, wd2t, b_d2, xbf);
    mfma_tail<<<NS/128, 256, 0, stream>>>(xbf, wr0t, wr1t, dirW0, dirW1, w_rgb, b_rgb, rgb);
}